// Round 1
// baseline (95.788 us; speedup 1.0000x reference)
//
#include <hip/hip_runtime.h>

#define BB 16
#define SS 512
#define HH 384
#define LL 2000
#define NBINS 256
#define H4 (HH/4)               // 96 float4 per row
#define OUT0 (BB*LL*HH)         // 12,288,000 floats (output 0)

// ---------------- Kernel 1: per-batch prep ----------------
// grid = B blocks, 512 threads. Computes cumsum of durations, mel_len,
// pitch/energy bin indices, combined embedding row, and the l -> s map.
__global__ __launch_bounds__(512) void prep_kernel(
    const float* __restrict__ log_dur,   // [B,S]
    const float* __restrict__ pitch,     // [B,S]
    const float* __restrict__ energy,    // [B,S]
    const float* __restrict__ ptab,      // [256,H]
    const float* __restrict__ etab,      // [256,H]
    int*   __restrict__ pos_map,         // [B,L]  (-1 if l >= total_len)
    float* __restrict__ comb,            // [B,H]
    float* __restrict__ out_mel)         // d_out + OUT0, [B] (stored as float)
{
    const int b = blockIdx.x;
    const int t = threadIdx.x;

    __shared__ int   cum[SS];
    __shared__ float red[SS];
    __shared__ int   s_idx[2];
    __shared__ int   s_total;

    // duration: max(rint(exp(ld)-1), 0)   (rintf = half-to-even, matches np.round)
    float ld = log_dur[b*SS + t];
    float e  = expf(ld) - 1.0f;
    int   d  = (int)fmaxf(rintf(e), 0.0f);

    // inclusive scan (Hillis-Steele)
    cum[t] = d;
    __syncthreads();
    for (int off = 1; off < SS; off <<= 1) {
        int v = (t >= off) ? cum[t - off] : 0;
        __syncthreads();
        cum[t] += v;
        __syncthreads();
    }

    // pitch mean -> bin index (truncation toward zero matches astype(int32))
    red[t] = pitch[b*SS + t];
    __syncthreads();
    for (int off = SS/2; off > 0; off >>= 1) {
        if (t < off) red[t] += red[t + off];
        __syncthreads();
    }
    if (t == 0) {
        int idx = (int)(red[0] * (1.0f/SS));
        s_idx[0] = idx < 0 ? 0 : (idx > NBINS-1 ? NBINS-1 : idx);
    }
    __syncthreads();

    // energy mean -> bin index
    red[t] = energy[b*SS + t];
    __syncthreads();
    for (int off = SS/2; off > 0; off >>= 1) {
        if (t < off) red[t] += red[t + off];
        __syncthreads();
    }
    if (t == 0) {
        int idx = (int)(red[0] * (1.0f/SS));
        s_idx[1] = idx < 0 ? 0 : (idx > NBINS-1 ? NBINS-1 : idx);
        s_total  = cum[SS-1];
        int mel  = s_total < LL ? s_total : LL;
        out_mel[b] = (float)mel;     // output 1 stored as float values
    }
    __syncthreads();

    const int pidx  = s_idx[0];
    const int eidx  = s_idx[1];
    const int total = s_total;

    // combined embedding row (broadcast over all L in the reference)
    if (t < HH) comb[b*HH + t] = ptab[pidx*HH + t] + etab[eidx*HH + t];

    // l -> s map via binary search on cum (first s with cum[s] > l)
    for (int l = t; l < LL; l += SS) {
        int sm = -1;
        if (l < total) {
            int lo = 0, hi = SS - 1;
            while (lo < hi) {
                int mid = (lo + hi) >> 1;
                if (cum[mid] > l) hi = mid; else lo = mid + 1;
            }
            sm = lo;
        }
        pos_map[b*LL + l] = sm;
    }
}

// ---------------- Kernel 2: expansion gather-add ----------------
// One float4 per thread, fully coalesced. 12000 blocks x 256 threads.
__global__ __launch_bounds__(256) void expand_kernel(
    const float4* __restrict__ enc,      // [B*S*H4]
    const int*    __restrict__ pos_map,  // [B*L]
    const float4* __restrict__ comb,     // [B*H4]
    float4*       __restrict__ out)      // [B*L*H4]
{
    const int i = blockIdx.x * 256 + threadIdx.x;
    if (i >= BB*LL*H4) return;
    const int h4  = i % H4;
    const int row = i / H4;              // b*L + l
    const int b   = row / LL;
    const int s   = pos_map[row];

    float4 c = comb[b*H4 + h4];
    float4 v = c;
    if (s >= 0) {
        float4 a = enc[(b*SS + s)*H4 + h4];
        v.x = a.x + c.x; v.y = a.y + c.y; v.z = a.z + c.z; v.w = a.w + c.w;
    }
    out[i] = v;
}

extern "C" void kernel_launch(void* const* d_in, const int* in_sizes, int n_in,
                              void* d_out, int out_size, void* d_ws, size_t ws_size,
                              hipStream_t stream) {
    const float* enc      = (const float*)d_in[0];   // [B,S,H]
    const float* log_dur  = (const float*)d_in[1];   // [B,S]
    const float* pitch    = (const float*)d_in[2];   // [B,S]
    const float* energy   = (const float*)d_in[3];   // [B,S]
    const float* ptab     = (const float*)d_in[4];   // [256,H]
    const float* etab     = (const float*)d_in[5];   // [256,H]
    // d_in[6] = max_mel_len scalar (2000), hardcoded

    float* out = (float*)d_out;

    // workspace layout
    int*   pos_map = (int*)d_ws;                            // 16*2000*4 = 128000 B
    float* comb    = (float*)((char*)d_ws + BB*LL*sizeof(int)); // 16-byte aligned

    prep_kernel<<<BB, SS, 0, stream>>>(log_dur, pitch, energy, ptab, etab,
                                       pos_map, comb, out + OUT0);

    const int n4 = BB*LL*H4;             // 3,072,000
    expand_kernel<<<(n4 + 255)/256, 256, 0, stream>>>(
        (const float4*)enc, pos_map, (const float4*)comb, (float4*)out);
}

// Round 2
// 95.170 us; speedup vs baseline: 1.0065x; 1.0065x over previous
//
#include <hip/hip_runtime.h>

#define BB 16
#define SS 512
#define HH 384
#define LL 2000
#define NBINS 256
#define H4 (HH/4)                 // 96 float4 per row
#define OUT0 (BB*LL*HH)           // floats in output 0
#define BLOCKS_PER_B 75
#define CHUNK ((LL*H4)/BLOCKS_PER_B)   // 192000/75 = 2560 = 10*256 exactly

// Single fused kernel: each block re-derives per-batch state (duration scan,
// pitch/energy bin, combined embedding row) then writes its chunk of the
// expanded output. Removes the prep kernel, its launch dependency, and the
// pos_map workspace round-trip.
__global__ __launch_bounds__(256) void fused_kernel(
    const float4* __restrict__ enc,      // [B*S*H4]
    const float*  __restrict__ log_dur,  // [B,S]
    const float*  __restrict__ pitch,    // [B,S]
    const float*  __restrict__ energy,   // [B,S]
    const float4* __restrict__ ptab,     // [256,H4]
    const float4* __restrict__ etab,     // [256,H4]
    float4*       __restrict__ out,      // [B*L*H4]
    float*        __restrict__ out_mel)  // [B] stored as float
{
    const int b     = blockIdx.x / BLOCKS_PER_B;
    const int chunk = blockIdx.x % BLOCKS_PER_B;
    const int t     = threadIdx.x;

    __shared__ int    sa[SS], sb[SS];     // scan ping-pong
    __shared__ float  red[256];
    __shared__ float4 comb4[H4];
    __shared__ int    s_pidx, s_eidx, s_total;

    // durations: max(rint(exp(ld)-1), 0)  (rintf = half-to-even = np.round)
    {
        float ld0 = log_dur[b*SS + t];
        float ld1 = log_dur[b*SS + t + 256];
        sa[t]     = (int)fmaxf(rintf(expf(ld0) - 1.0f), 0.0f);
        sa[t+256] = (int)fmaxf(rintf(expf(ld1) - 1.0f), 0.0f);
    }
    __syncthreads();

    // inclusive scan over 512 ints, ping-pong Hillis-Steele (int add: exact)
    int* src = sa; int* dst = sb;
    for (int off = 1; off < SS; off <<= 1) {
        for (int i = t; i < SS; i += 256) {
            int v = src[i];
            if (i >= off) v += src[i - off];
            dst[i] = v;
        }
        __syncthreads();
        int* tmp = src; src = dst; dst = tmp;
    }
    const int* cum = src;   // final inclusive cumsum

    // pitch mean -> bin (summation order identical to previous passing kernel)
    red[t] = pitch[b*SS + t] + pitch[b*SS + t + 256];
    __syncthreads();
    for (int off = 128; off > 0; off >>= 1) {
        if (t < off) red[t] += red[t + off];
        __syncthreads();
    }
    if (t == 0) {
        int idx = (int)(red[0] * (1.0f/SS));
        s_pidx = idx < 0 ? 0 : (idx > NBINS-1 ? NBINS-1 : idx);
    }
    __syncthreads();

    // energy mean -> bin
    red[t] = energy[b*SS + t] + energy[b*SS + t + 256];
    __syncthreads();
    for (int off = 128; off > 0; off >>= 1) {
        if (t < off) red[t] += red[t + off];
        __syncthreads();
    }
    if (t == 0) {
        int idx = (int)(red[0] * (1.0f/SS));
        s_eidx  = idx < 0 ? 0 : (idx > NBINS-1 ? NBINS-1 : idx);
        s_total = cum[SS-1];
        if (chunk == 0) {
            int mel = s_total < LL ? s_total : LL;
            out_mel[b] = (float)mel;   // output 1, stored as float values
        }
    }
    __syncthreads();

    // combined embedding row (broadcast over all L positions in the reference)
    if (t < H4) {
        float4 p = ptab[s_pidx*H4 + t];
        float4 q = etab[s_eidx*H4 + t];
        comb4[t] = make_float4(p.x+q.x, p.y+q.y, p.z+q.z, p.w+q.w);
    }
    __syncthreads();

    const int total = s_total;
    const int base  = chunk * CHUNK;
    const int out_b = b * (LL*H4);

    #pragma unroll 2
    for (int k = 0; k < CHUNK; k += 256) {
        int idx = base + k + t;           // flat index in [0, L*H4)
        int h4  = idx % H4;
        int l   = idx / H4;
        float4 v = comb4[h4];
        if (l < total) {
            // first s with cum[s] > l
            int lo = 0, hi = SS - 1;
            while (lo < hi) {
                int mid = (lo + hi) >> 1;
                if (cum[mid] > l) hi = mid; else lo = mid + 1;
            }
            float4 a = enc[(b*SS + lo)*H4 + h4];
            v.x += a.x; v.y += a.y; v.z += a.z; v.w += a.w;
        }
        out[out_b + idx] = v;
    }
}

extern "C" void kernel_launch(void* const* d_in, const int* in_sizes, int n_in,
                              void* d_out, int out_size, void* d_ws, size_t ws_size,
                              hipStream_t stream) {
    const float* enc     = (const float*)d_in[0];
    const float* log_dur = (const float*)d_in[1];
    const float* pitch   = (const float*)d_in[2];
    const float* energy  = (const float*)d_in[3];
    const float* ptab    = (const float*)d_in[4];
    const float* etab    = (const float*)d_in[5];
    // d_in[6] = max_mel_len scalar (2000), hardcoded
    (void)d_ws; (void)ws_size;

    float* out = (float*)d_out;

    fused_kernel<<<BB*BLOCKS_PER_B, 256, 0, stream>>>(
        (const float4*)enc, log_dur, pitch, energy,
        (const float4*)ptab, (const float4*)etab,
        (float4*)out, out + OUT0);
}